// Round 3
// baseline (558.402 us; speedup 1.0000x reference)
//
#include <hip/hip_runtime.h>

#define D_FEAT 64
#define LOG_BKT 7
#define BKT_W 128               // nodes per coarse bucket
#define PART_CHUNK 16384        // edges per partition workgroup
#define ACC_CHUNK 2048          // entries staged in LDS per accum iteration

// ---------------- fast path ----------------

// deg[i] = 1.0 (self loop); histR[b] = 0
__global__ void k_init(float* __restrict__ deg, unsigned* __restrict__ histR, int n, int nBkt) {
    int i = blockIdx.x * blockDim.x + threadIdx.x;
    if (i < n) deg[i] = 1.0f;
    if (i < nBkt) histR[i] = 0u;
}

// fused: deg[col[e]] += 1 (global atomics) + LDS-privatized coarse hist of row>>LOG_BKT
__global__ void k_histdeg(const int* __restrict__ row, const int* __restrict__ col,
                          float* __restrict__ deg, unsigned* __restrict__ histR,
                          int E, int nBkt) {
    __shared__ unsigned ldsH[1024];
    int t = threadIdx.x;
    for (int i = t; i < nBkt; i += 256) ldsH[i] = 0u;
    __syncthreads();
    long long c0 = (long long)blockIdx.x * PART_CHUNK;
    for (int k = 0; k < PART_CHUNK / 256; ++k) {
        long long e = c0 + (long long)k * 256 + t;
        if (e < E) {
            int r = row[e];
            atomicAdd(&ldsH[r >> LOG_BKT], 1u);
            atomicAdd(&deg[col[e]], 1.0f);
        }
    }
    __syncthreads();
    for (int b = t; b < nBkt; b += 256) {
        unsigned c = ldsH[b];
        if (c) atomicAdd(&histR[b], c);
    }
}

// deg -> rsqrt(deg) in place
__global__ void k_deg_to_dis(float* __restrict__ deg, int n) {
    int i = blockIdx.x * blockDim.x + threadIdx.x;
    if (i < n) deg[i] = rsqrtf(deg[i]);
}

// single-block exclusive scan of histR[nBkt] -> baseR[nBkt+1]; cursorR = baseR
// requires nBkt <= 1024
__global__ void k_scan(const unsigned* __restrict__ histR, unsigned* __restrict__ baseR,
                       unsigned* __restrict__ cursorR, int nBkt, int E) {
    __shared__ unsigned lds[256];
    int t = threadIdx.x;
    unsigned v[4];
    unsigned s = 0;
    for (int k = 0; k < 4; ++k) {
        int i = t * 4 + k;
        v[k] = (i < nBkt) ? histR[i] : 0u;
        s += v[k];
    }
    lds[t] = s;
    __syncthreads();
    for (int d = 1; d < 256; d <<= 1) {
        unsigned add = (t >= d) ? lds[t - d] : 0u;
        __syncthreads();
        lds[t] += add;
        __syncthreads();
    }
    unsigned excl = lds[t] - s;
    unsigned run = excl;
    for (int k = 0; k < 4; ++k) {
        int i = t * 4 + k;
        if (i < nBkt) { baseR[i] = run; cursorR[i] = run; }
        if (i == nBkt) baseR[i] = (unsigned)E;
        run += v[k];
    }
    if (t == 255) {
        // ensure baseR[nBkt] written even if nBkt == 1024
        if (nBkt == 1024) baseR[1024] = (unsigned)E;
    }
}

// partition edges into coarse buckets: entries[pos] = (row&(BKT_W-1))<<17 | col
__global__ void k_part(const int* __restrict__ row, const int* __restrict__ col,
                       unsigned* __restrict__ cursorR, unsigned* __restrict__ entries,
                       int E, int nBkt) {
    __shared__ unsigned ldsH[1024];
    int t = threadIdx.x;
    for (int i = t; i < nBkt; i += 256) ldsH[i] = 0u;
    __syncthreads();
    long long c0 = (long long)blockIdx.x * PART_CHUNK;
    // pass 1: count
    for (int k = 0; k < PART_CHUNK / 256; ++k) {
        long long e = c0 + (long long)k * 256 + t;
        if (e < E) atomicAdd(&ldsH[row[e] >> LOG_BKT], 1u);
    }
    __syncthreads();
    // reserve global space per bin; store base into ldsH (reuse as cursor)
    for (int b = t; b < nBkt; b += 256) {
        unsigned c = ldsH[b];
        ldsH[b] = c ? atomicAdd(&cursorR[b], c) : 0u;
    }
    __syncthreads();
    // pass 2: write packed entries
    for (int k = 0; k < PART_CHUNK / 256; ++k) {
        long long e = c0 + (long long)k * 256 + t;
        if (e < E) {
            int r = row[e];
            int b = r >> LOG_BKT;
            unsigned pos = atomicAdd(&ldsH[b], 1u);
            entries[pos] = ((unsigned)(r & (BKT_W - 1)) << 17) | (unsigned)col[e];
        }
    }
}

// one WG per coarse bucket: LDS tile accumulation, no global atomics, one write of out
__global__ void __launch_bounds__(256) k_accum(
        const float* __restrict__ x, const float* __restrict__ dis,
        const unsigned* __restrict__ baseR, const unsigned* __restrict__ entries,
        float* __restrict__ out, int n) {
    __shared__ float tile[BKT_W * D_FEAT];   // 32 KB
    __shared__ unsigned ebuf[ACC_CHUNK];     // 8 KB
    int b = blockIdx.x;
    int t = threadIdx.x;
    int lane = t & 63;
    int wv = t >> 6;                         // 4 waves
    int node0 = b << LOG_BKT;

    // init tile with self-loop term (factor dis[r] applied at writeout):
    // y[r] = dis[r]*x[r] + sum dis[c]*x[c];  out[r] = dis[r]*y[r]
    for (int lr = wv; lr < BKT_W; lr += 4) {
        int node = node0 + lr;
        float v = 0.0f;
        if (node < n) v = dis[node] * x[(size_t)node * D_FEAT + lane];
        tile[lr * D_FEAT + lane] = v;
    }
    unsigned s = baseR[b], e_ = baseR[b + 1];
    for (unsigned chunk = s; chunk < e_; chunk += ACC_CHUNK) {
        int cn = (int)min((unsigned)ACC_CHUNK, e_ - chunk);
        __syncthreads();
        for (int i = t; i < cn; i += 256) ebuf[i] = entries[chunk + i];
        __syncthreads();
        int i = wv;
        for (; i + 4 < cn; i += 8) {
            unsigned e0 = ebuf[i], e1 = ebuf[i + 4];
            int lr0 = e0 >> 17, c0 = e0 & 0x1FFFF;
            int lr1 = e1 >> 17, c1 = e1 & 0x1FFFF;
            float w0 = dis[c0], w1 = dis[c1];
            float xv0 = x[(size_t)c0 * D_FEAT + lane];
            float xv1 = x[(size_t)c1 * D_FEAT + lane];
            atomicAdd(&tile[lr0 * D_FEAT + lane], w0 * xv0);
            atomicAdd(&tile[lr1 * D_FEAT + lane], w1 * xv1);
        }
        for (; i < cn; i += 4) {
            unsigned e0 = ebuf[i];
            int lr0 = e0 >> 17, c0 = e0 & 0x1FFFF;
            atomicAdd(&tile[lr0 * D_FEAT + lane], dis[c0] * x[(size_t)c0 * D_FEAT + lane]);
        }
    }
    __syncthreads();
    for (int lr = wv; lr < BKT_W; lr += 4) {
        int node = node0 + lr;
        if (node < n) out[(size_t)node * D_FEAT + lane] = dis[node] * tile[lr * D_FEAT + lane];
    }
}

// ---------------- fallback path (round-1 atomic scatter) ----------------

__global__ void k_init_deg(float* __restrict__ deg, int n) {
    int i = blockIdx.x * blockDim.x + threadIdx.x;
    if (i < n) deg[i] = 1.0f;
}
__global__ void k_count_deg(const int* __restrict__ col, float* __restrict__ deg, int E) {
    int e = blockIdx.x * blockDim.x + threadIdx.x;
    if (e < E) atomicAdd(&deg[col[e]], 1.0f);
}
__global__ void k_self_init(const float* __restrict__ x, const float* __restrict__ dis,
                            float* __restrict__ out, int total) {
    int idx = blockIdx.x * blockDim.x + threadIdx.x;
    if (idx < total) {
        int node = idx >> 6;
        float s = dis[node];
        out[idx] = s * s * x[idx];
    }
}
__global__ void k_scatter(const int* __restrict__ row, const int* __restrict__ col,
                          const float* __restrict__ x, const float* __restrict__ dis,
                          float* __restrict__ out, int E) {
    int gtid = blockIdx.x * blockDim.x + threadIdx.x;
    int edge = gtid >> 6;
    int lane = threadIdx.x & 63;
    if (edge < E) {
        int r = row[edge];
        int c = col[edge];
        float nrm = dis[r] * dis[c];
        atomicAdd(&out[r * D_FEAT + lane], nrm * x[c * D_FEAT + lane]);
    }
}

extern "C" void kernel_launch(void* const* d_in, const int* in_sizes, int n_in,
                              void* d_out, int out_size, void* d_ws, size_t ws_size,
                              hipStream_t stream) {
    const float* x = (const float*)d_in[0];
    const int* ei = (const int*)d_in[1];

    const int N = in_sizes[0] / D_FEAT;   // 100000
    const int E = in_sizes[1] / 2;        // 1000000
    const int* row = ei;
    const int* col = ei + E;

    float* out = (float*)d_out;
    const int B = 256;
    const int nBkt = (N + BKT_W - 1) >> LOG_BKT;

    // ws: deg[N] | histR[nBkt] | baseR[nBkt+1] | cursorR[nBkt] | entries[E]
    size_t need = ((size_t)N + 3 * (size_t)nBkt + 1 + (size_t)E) * 4;

    if (N <= 131072 && nBkt <= 1024 && ws_size >= need) {
        float*    deg     = (float*)d_ws;
        unsigned* histR   = (unsigned*)(deg + N);
        unsigned* baseR   = histR + nBkt;
        unsigned* cursorR = baseR + (nBkt + 1);
        unsigned* entries = cursorR + nBkt;

        int nWG_E = (E + PART_CHUNK - 1) / PART_CHUNK;

        k_init<<<(max(N, nBkt) + B - 1) / B, B, 0, stream>>>(deg, histR, N, nBkt);
        k_histdeg<<<nWG_E, B, 0, stream>>>(row, col, deg, histR, E, nBkt);
        k_scan<<<1, B, 0, stream>>>(histR, baseR, cursorR, nBkt, E);
        k_part<<<nWG_E, B, 0, stream>>>(row, col, cursorR, entries, E, nBkt);
        k_deg_to_dis<<<(N + B - 1) / B, B, 0, stream>>>(deg, N);
        k_accum<<<nBkt, B, 0, stream>>>(x, deg, baseR, entries, out, N);
    } else {
        // fallback: atomic scatter (needs only N floats of ws)
        float* deg = (float*)d_ws;
        k_init_deg<<<(N + B - 1) / B, B, 0, stream>>>(deg, N);
        k_count_deg<<<(E + B - 1) / B, B, 0, stream>>>(col, deg, E);
        k_deg_to_dis<<<(N + B - 1) / B, B, 0, stream>>>(deg, N);
        int total = N * D_FEAT;
        k_self_init<<<(total + B - 1) / B, B, 0, stream>>>(x, deg, out, total);
        long long st = (long long)E * 64;
        k_scatter<<<(int)((st + B - 1) / B), B, 0, stream>>>(row, col, x, deg, out, E);
    }
}

// Round 4
// 213.619 us; speedup vs baseline: 2.6140x; 2.6140x over previous
//
#include <hip/hip_runtime.h>
#include <hip/hip_fp16.h>

#define D_FEAT 64
#define LOG_BKT 7
#define BKT_W 128
#define HIST_CHUNK 8192
#define PART_CHUNK 16384
#define CSR_CAP 2048

// ---------------- build phase ----------------

// deg[i] = 1.0 (self loop); histR/flags = 0
__global__ void k_init(float* __restrict__ deg, unsigned* __restrict__ histR,
                       unsigned* __restrict__ flags, int n, int nBkt) {
    int i = blockIdx.x * blockDim.x + threadIdx.x;
    if (i < n) deg[i] = 1.0f;
    if (i < nBkt) { histR[i] = 0u; flags[i] = 0u; }
}

// x (f32) -> xh (fp16), vectorized 4-wide
__global__ void k_tohalf(const float* __restrict__ x, __half* __restrict__ xh, int total) {
    int i = (blockIdx.x * blockDim.x + threadIdx.x) * 4;
    if (i + 3 < total) {
        float4 v = *(const float4*)(x + i);
        __half2 p0 = __halves2half2(__float2half(v.x), __float2half(v.y));
        __half2 p1 = __halves2half2(__float2half(v.z), __float2half(v.w));
        *(__half2*)(xh + i) = p0;
        *(__half2*)(xh + i + 2) = p1;
    } else {
        for (int k = i; k < total; ++k) xh[k] = __float2half(x[k]);
    }
}

// fused: deg[col[e]] += 1 (global atomics) + LDS-privatized coarse hist of row>>LOG_BKT
__global__ void k_histdeg(const int* __restrict__ row, const int* __restrict__ col,
                          float* __restrict__ deg, unsigned* __restrict__ histR,
                          int E, int nBkt) {
    __shared__ unsigned ldsH[1024];
    int t = threadIdx.x;
    for (int i = t; i < nBkt; i += 256) ldsH[i] = 0u;
    __syncthreads();
    long long c0 = (long long)blockIdx.x * HIST_CHUNK;
    for (int k = 0; k < HIST_CHUNK / 256; ++k) {
        long long e = c0 + (long long)k * 256 + t;
        if (e < E) {
            atomicAdd(&ldsH[row[e] >> LOG_BKT], 1u);
            atomicAdd(&deg[col[e]], 1.0f);
        }
    }
    __syncthreads();
    for (int b = t; b < nBkt; b += 256) {
        unsigned c = ldsH[b];
        if (c) atomicAdd(&histR[b], c);
    }
}

// deg -> rsqrt(deg) in place
__global__ void k_deg_to_dis(float* __restrict__ deg, int n) {
    int i = blockIdx.x * blockDim.x + threadIdx.x;
    if (i < n) deg[i] = rsqrtf(deg[i]);
}

// single-block exclusive scan of histR[nBkt] -> baseR; cursorR = baseR; sentinels
__global__ void k_scan(const unsigned* __restrict__ histR, unsigned* __restrict__ baseR,
                       unsigned* __restrict__ cursorR, unsigned* __restrict__ nodeBeg,
                       int nBkt, int E, int N) {
    __shared__ unsigned lds[256];
    int t = threadIdx.x;
    unsigned v[4];
    unsigned s = 0;
    for (int k = 0; k < 4; ++k) {
        int i = t * 4 + k;
        v[k] = (i < nBkt) ? histR[i] : 0u;
        s += v[k];
    }
    lds[t] = s;
    __syncthreads();
    for (int d = 1; d < 256; d <<= 1) {
        unsigned add = (t >= d) ? lds[t - d] : 0u;
        __syncthreads();
        lds[t] += add;
        __syncthreads();
    }
    unsigned run = lds[t] - s;
    for (int k = 0; k < 4; ++k) {
        int i = t * 4 + k;
        if (i < nBkt) { baseR[i] = run; cursorR[i] = run; }
        if (i == nBkt) baseR[i] = (unsigned)E;
        run += v[k];
    }
    if (t == 255) {
        if (nBkt == 1024) baseR[1024] = (unsigned)E;
        nodeBeg[N] = (unsigned)E;   // sentinel (also rewritten by last bucket's localcsr)
    }
}

// partition edges into coarse buckets: entries[pos] = (row&127)<<17 | col
__global__ void k_part(const int* __restrict__ row, const int* __restrict__ col,
                       unsigned* __restrict__ cursorR, unsigned* __restrict__ entries,
                       int E, int nBkt) {
    __shared__ unsigned ldsH[1024];
    int t = threadIdx.x;
    for (int i = t; i < nBkt; i += 256) ldsH[i] = 0u;
    __syncthreads();
    long long c0 = (long long)blockIdx.x * PART_CHUNK;
    for (int k = 0; k < PART_CHUNK / 256; ++k) {
        long long e = c0 + (long long)k * 256 + t;
        if (e < E) atomicAdd(&ldsH[row[e] >> LOG_BKT], 1u);
    }
    __syncthreads();
    for (int b = t; b < nBkt; b += 256) {
        unsigned c = ldsH[b];
        ldsH[b] = c ? atomicAdd(&cursorR[b], c) : 0u;
    }
    __syncthreads();
    for (int k = 0; k < PART_CHUNK / 256; ++k) {
        long long e = c0 + (long long)k * 256 + t;
        if (e < E) {
            int r = row[e];
            int b = r >> LOG_BKT;
            unsigned pos = atomicAdd(&ldsH[b], 1u);
            entries[pos] = ((unsigned)(r & (BKT_W - 1)) << 17) | (unsigned)col[e];
        }
    }
}

// one small WG per bucket: sort its entries into per-node CSR order inside LDS,
// strip lr tag (entries become plain col), emit nodeBeg.
__global__ void __launch_bounds__(256) k_localcsr(
        unsigned* __restrict__ entries, const unsigned* __restrict__ baseR,
        unsigned* __restrict__ nodeBeg, unsigned* __restrict__ flags, int N) {
    __shared__ unsigned ebuf[CSR_CAP];
    __shared__ unsigned sbuf[CSR_CAP];
    __shared__ unsigned hist[BKT_W];
    __shared__ unsigned scanT[BKT_W];
    __shared__ unsigned cur[BKT_W];
    int b = blockIdx.x;
    int t = threadIdx.x;
    unsigned s = baseR[b], e_ = baseR[b + 1];
    int cnt = (int)(e_ - s);
    int node0 = b << LOG_BKT;
    if (t < BKT_W) hist[t] = 0u;
    __syncthreads();

    bool fast = (cnt <= CSR_CAP);
    if (fast) {
        for (int i = t; i < cnt; i += 256) {
            unsigned v = entries[s + i];
            ebuf[i] = v;
            atomicAdd(&hist[v >> 17], 1u);
        }
    } else {
        for (unsigned base = s; base < e_; base += CSR_CAP) {
            int cn = (int)(((e_ - base) < CSR_CAP) ? (e_ - base) : CSR_CAP);
            for (int i = t; i < cn; i += 256) atomicAdd(&hist[entries[base + i] >> 17], 1u);
        }
    }
    __syncthreads();
    // inclusive scan of hist -> scanT
    if (t < BKT_W) scanT[t] = hist[t];
    __syncthreads();
    for (int d = 1; d < BKT_W; d <<= 1) {
        unsigned v = 0;
        if (t < BKT_W && t >= d) v = scanT[t - d];
        __syncthreads();
        if (t < BKT_W) scanT[t] += v;
        __syncthreads();
    }
    if (t < BKT_W) {
        unsigned excl = scanT[t] - hist[t];
        cur[t] = excl;
        int node = node0 + t;
        if (node <= N) nodeBeg[node] = s + excl;
    }
    __syncthreads();
    if (fast) {
        for (int i = t; i < cnt; i += 256) {
            unsigned v = ebuf[i];
            unsigned pos = atomicAdd(&cur[v >> 17], 1u);
            sbuf[pos] = v & 0x1FFFFu;   // strip lr: keep col only
        }
        __syncthreads();
        for (int i = t; i < cnt; i += 256) entries[s + i] = sbuf[i];
    } else {
        if (t == 0) flags[b] = 1u;      // gather falls back to filter-scan
    }
}

// per-node wave gather off CSR; lane = feature. No atomics, one write of out.
template <bool HALF>
__global__ void __launch_bounds__(256) k_gather(
        const float* __restrict__ x, const __half* __restrict__ xh,
        const float* __restrict__ dis, const unsigned* __restrict__ nodeBeg,
        const unsigned* __restrict__ baseR, const unsigned* __restrict__ flags,
        const unsigned* __restrict__ entries, float* __restrict__ out, int n) {
    int r = (blockIdx.x * blockDim.x + threadIdx.x) >> 6;
    int lane = threadIdx.x & 63;
    if (r >= n) return;
    float dr = dis[r];
    float acc = dr * dr * x[(size_t)r * D_FEAT + lane];   // self-loop term, f32
    int b = r >> LOG_BKT;
    if (!flags[b]) {
        unsigned j = nodeBeg[r], e_ = nodeBeg[r + 1];
        for (; j + 1 < e_; j += 2) {
            unsigned c0 = entries[j], c1 = entries[j + 1];
            float w0 = dr * dis[c0];
            float w1 = dr * dis[c1];
            float v0, v1;
            if (HALF) {
                v0 = __half2float(xh[(size_t)c0 * D_FEAT + lane]);
                v1 = __half2float(xh[(size_t)c1 * D_FEAT + lane]);
            } else {
                v0 = x[(size_t)c0 * D_FEAT + lane];
                v1 = x[(size_t)c1 * D_FEAT + lane];
            }
            acc = fmaf(w0, v0, acc);
            acc = fmaf(w1, v1, acc);
        }
        if (j < e_) {
            unsigned c = entries[j];
            float v = HALF ? __half2float(xh[(size_t)c * D_FEAT + lane])
                           : x[(size_t)c * D_FEAT + lane];
            acc = fmaf(dr * dis[c], v, acc);
        }
    } else {
        unsigned lr = (unsigned)(r & (BKT_W - 1));
        for (unsigned j = baseR[b]; j < baseR[b + 1]; ++j) {
            unsigned v = entries[j];
            if ((v >> 17) == lr) {
                unsigned c = v & 0x1FFFFu;
                float xv = HALF ? __half2float(xh[(size_t)c * D_FEAT + lane])
                                : x[(size_t)c * D_FEAT + lane];
                acc = fmaf(dr * dis[c], xv, acc);
            }
        }
    }
    out[(size_t)r * D_FEAT + lane] = acc;
}

// ---------------- fallback path (round-1 atomic scatter) ----------------

__global__ void k_init_deg(float* __restrict__ deg, int n) {
    int i = blockIdx.x * blockDim.x + threadIdx.x;
    if (i < n) deg[i] = 1.0f;
}
__global__ void k_count_deg(const int* __restrict__ col, float* __restrict__ deg, int E) {
    int e = blockIdx.x * blockDim.x + threadIdx.x;
    if (e < E) atomicAdd(&deg[col[e]], 1.0f);
}
__global__ void k_self_init(const float* __restrict__ x, const float* __restrict__ dis,
                            float* __restrict__ out, int total) {
    int idx = blockIdx.x * blockDim.x + threadIdx.x;
    if (idx < total) {
        int node = idx >> 6;
        float s = dis[node];
        out[idx] = s * s * x[idx];
    }
}
__global__ void k_scatter(const int* __restrict__ row, const int* __restrict__ col,
                          const float* __restrict__ x, const float* __restrict__ dis,
                          float* __restrict__ out, int E) {
    int gtid = blockIdx.x * blockDim.x + threadIdx.x;
    int edge = gtid >> 6;
    int lane = threadIdx.x & 63;
    if (edge < E) {
        int r = row[edge];
        int c = col[edge];
        float nrm = dis[r] * dis[c];
        atomicAdd(&out[r * D_FEAT + lane], nrm * x[c * D_FEAT + lane]);
    }
}

extern "C" void kernel_launch(void* const* d_in, const int* in_sizes, int n_in,
                              void* d_out, int out_size, void* d_ws, size_t ws_size,
                              hipStream_t stream) {
    const float* x = (const float*)d_in[0];
    const int* ei = (const int*)d_in[1];

    const int N = in_sizes[0] / D_FEAT;   // 100000
    const int E = in_sizes[1] / 2;        // 1000000
    const int* row = ei;
    const int* col = ei + E;

    float* out = (float*)d_out;
    const int B = 256;
    const int nBkt = (N + BKT_W - 1) >> LOG_BKT;

    // ws words: deg[N] | histR[1024] | baseR[1025] | cursorR[1024] | flags[1024]
    //           | nodeBeg[N+1] | entries[E] | xh[N*64 halves]
    size_t baseWords = (size_t)N + 1024 + 1025 + 1024 + 1024 + (size_t)(N + 1) + (size_t)E;
    size_t needMid  = baseWords * 4;
    size_t needFast = needMid + (size_t)N * D_FEAT * 2;

    if (N <= 131072 && nBkt <= 1024 && ws_size >= needMid) {
        bool useHalf = (ws_size >= needFast);
        float*    deg     = (float*)d_ws;
        unsigned* histR   = (unsigned*)(deg + N);
        unsigned* baseR   = histR + 1024;
        unsigned* cursorR = baseR + 1025;
        unsigned* flags   = cursorR + 1024;
        unsigned* nodeBeg = flags + 1024;
        unsigned* entries = nodeBeg + (N + 1);
        __half*   xh      = (__half*)(entries + E);

        k_init<<<(N + B - 1) / B, B, 0, stream>>>(deg, histR, flags, N, nBkt);
        if (useHalf) {
            int total = N * D_FEAT;
            k_tohalf<<<(total / 4 + B - 1) / B, B, 0, stream>>>(x, xh, total);
        }
        k_histdeg<<<(E + HIST_CHUNK - 1) / HIST_CHUNK, B, 0, stream>>>(row, col, deg, histR, E, nBkt);
        k_scan<<<1, B, 0, stream>>>(histR, baseR, cursorR, nodeBeg, nBkt, E, N);
        k_part<<<(E + PART_CHUNK - 1) / PART_CHUNK, B, 0, stream>>>(row, col, cursorR, entries, E, nBkt);
        k_deg_to_dis<<<(N + B - 1) / B, B, 0, stream>>>(deg, N);
        k_localcsr<<<nBkt, B, 0, stream>>>(entries, baseR, nodeBeg, flags, N);

        long long gthreads = (long long)N * 64;
        int gblocks = (int)((gthreads + B - 1) / B);
        if (useHalf)
            k_gather<true><<<gblocks, B, 0, stream>>>(x, xh, deg, nodeBeg, baseR, flags, entries, out, N);
        else
            k_gather<false><<<gblocks, B, 0, stream>>>(x, xh, deg, nodeBeg, baseR, flags, entries, out, N);
    } else {
        // fallback: atomic scatter (needs only N floats of ws)
        float* deg = (float*)d_ws;
        k_init_deg<<<(N + B - 1) / B, B, 0, stream>>>(deg, N);
        k_count_deg<<<(E + B - 1) / B, B, 0, stream>>>(col, deg, E);
        k_deg_to_dis<<<(N + B - 1) / B, B, 0, stream>>>(deg, N);
        int total = N * D_FEAT;
        k_self_init<<<(total + B - 1) / B, B, 0, stream>>>(x, deg, out, total);
        long long st = (long long)E * 64;
        k_scatter<<<(int)((st + B - 1) / B), B, 0, stream>>>(row, col, x, deg, out, E);
    }
}

// Round 5
// 160.886 us; speedup vs baseline: 3.4708x; 1.3278x over previous
//
#include <hip/hip_runtime.h>
#include <hip/hip_fp16.h>

#define D_FEAT 64
#define LOG_BKT 7
#define BKT_W 128
#define HIST_CHUNK 16384
#define PART_CHUNK 16384
#define CSR_CAP 2048

// ---------------- build phase ----------------

// zero histRC[2048] and flags[1024]
__global__ void k_zero(unsigned* __restrict__ histRC, unsigned* __restrict__ flags) {
    int i = blockIdx.x * blockDim.x + threadIdx.x;
    if (i < 2048) histRC[i] = 0u;
    if (i < 1024) flags[i] = 0u;
}

// LDS-privatized coarse hist of row>>7 (bins 0..1023) and col>>7 (bins 1024..2047)
__global__ void k_hist2(const int* __restrict__ row, const int* __restrict__ col,
                        unsigned* __restrict__ histRC, int E) {
    __shared__ unsigned h[2048];
    int t = threadIdx.x;
    for (int i = t; i < 2048; i += 256) h[i] = 0u;
    __syncthreads();
    long long c0 = (long long)blockIdx.x * HIST_CHUNK;
    for (int k = 0; k < HIST_CHUNK / 256; ++k) {
        long long e = c0 + (long long)k * 256 + t;
        if (e < E) {
            atomicAdd(&h[row[e] >> LOG_BKT], 1u);
            atomicAdd(&h[1024 + (col[e] >> LOG_BKT)], 1u);
        }
    }
    __syncthreads();
    for (int i = t; i < 2048; i += 256) {
        unsigned c = h[i];
        if (c) atomicAdd(&histRC[i], c);
    }
}

// grid=2: block 0 scans row bins -> baseR/cursorR; block 1 scans col bins -> baseC/cursorC
__global__ void k_scan(const unsigned* __restrict__ histRC,
                       unsigned* __restrict__ baseR, unsigned* __restrict__ baseC,
                       unsigned* __restrict__ cursorR, unsigned* __restrict__ cursorC,
                       unsigned* __restrict__ nodeBeg, int E, int N) {
    __shared__ unsigned lds[256];
    const unsigned* hist = histRC + (size_t)blockIdx.x * 1024;
    unsigned* base = blockIdx.x ? baseC : baseR;
    unsigned* cur  = blockIdx.x ? cursorC : cursorR;
    int t = threadIdx.x;
    unsigned v[4];
    unsigned s = 0;
    for (int k = 0; k < 4; ++k) { v[k] = hist[t * 4 + k]; s += v[k]; }
    lds[t] = s;
    __syncthreads();
    for (int d = 1; d < 256; d <<= 1) {
        unsigned a = (t >= d) ? lds[t - d] : 0u;
        __syncthreads();
        lds[t] += a;
        __syncthreads();
    }
    unsigned run = lds[t] - s;
    for (int k = 0; k < 4; ++k) {
        int i = t * 4 + k;
        base[i] = run; cur[i] = run;
        run += v[k];
    }
    if (t == 255) {
        base[1024] = (unsigned)E;
        if (blockIdx.x == 0) nodeBeg[N] = (unsigned)E;
    }
}

// fused partition: row-entries (4B: (row&127)<<17|col) and col-bytes (1B: col&127)
__global__ void k_part2(const int* __restrict__ row, const int* __restrict__ col,
                        unsigned* __restrict__ cursorR, unsigned* __restrict__ cursorC,
                        unsigned* __restrict__ entries, unsigned char* __restrict__ colslab,
                        int E) {
    __shared__ unsigned ldsR[1024];
    __shared__ unsigned ldsC[1024];
    int t = threadIdx.x;
    for (int i = t; i < 1024; i += 256) { ldsR[i] = 0u; ldsC[i] = 0u; }
    __syncthreads();
    long long c0 = (long long)blockIdx.x * PART_CHUNK;
    for (int k = 0; k < PART_CHUNK / 256; ++k) {
        long long e = c0 + (long long)k * 256 + t;
        if (e < E) {
            atomicAdd(&ldsR[row[e] >> LOG_BKT], 1u);
            atomicAdd(&ldsC[col[e] >> LOG_BKT], 1u);
        }
    }
    __syncthreads();
    for (int i = t; i < 1024; i += 256) {
        unsigned c = ldsR[i]; ldsR[i] = c ? atomicAdd(&cursorR[i], c) : 0u;
        c = ldsC[i];          ldsC[i] = c ? atomicAdd(&cursorC[i], c) : 0u;
    }
    __syncthreads();
    for (int k = 0; k < PART_CHUNK / 256; ++k) {
        long long e = c0 + (long long)k * 256 + t;
        if (e < E) {
            int r = row[e], c = col[e];
            unsigned pr = atomicAdd(&ldsR[r >> LOG_BKT], 1u);
            entries[pr] = ((unsigned)(r & (BKT_W - 1)) << 17) | (unsigned)c;
            unsigned pc = atomicAdd(&ldsC[c >> LOG_BKT], 1u);
            colslab[pc] = (unsigned char)(c & (BKT_W - 1));
        }
    }
}

// one WG per col-bucket: LDS count of each local col value -> dis[node] = rsqrt(cnt+1)
__global__ void k_colcount(const unsigned char* __restrict__ colslab,
                           const unsigned* __restrict__ baseC,
                           float* __restrict__ dis, int N) {
    __shared__ unsigned h[BKT_W];
    int b = blockIdx.x, t = threadIdx.x;
    if (t < BKT_W) h[t] = 0u;
    __syncthreads();
    unsigned s = baseC[b], e_ = baseC[b + 1];
    for (unsigned i = s + t; i < e_; i += 256) atomicAdd(&h[colslab[i]], 1u);
    __syncthreads();
    if (t < BKT_W) {
        int node = (b << LOG_BKT) + t;
        if (node < N) dis[node] = rsqrtf((float)(h[t] + 1u));
    }
}

// xs = dis * x, fp16 (pre-scaled gather source). One thread per 4 features.
__global__ void k_scale(const float* __restrict__ x, const float* __restrict__ dis,
                        __half* __restrict__ xs, int N) {
    int i = blockIdx.x * blockDim.x + threadIdx.x;
    if (i >= N * (D_FEAT / 4)) return;
    int node = i >> 4;
    float d = dis[node];
    float4 v = ((const float4*)x)[i];
    __half2 p0 = __floats2half2_rn(d * v.x, d * v.y);
    __half2 p1 = __floats2half2_rn(d * v.z, d * v.w);
    ((__half2*)xs)[i * 2]     = p0;
    ((__half2*)xs)[i * 2 + 1] = p1;
}

// one WG per row-bucket: sort its entries into per-node CSR order in LDS,
// strip lr tag (entries become plain col), emit nodeBeg.
__global__ void __launch_bounds__(256) k_localcsr(
        unsigned* __restrict__ entries, const unsigned* __restrict__ baseR,
        unsigned* __restrict__ nodeBeg, unsigned* __restrict__ flags, int N) {
    __shared__ unsigned ebuf[CSR_CAP];
    __shared__ unsigned sbuf[CSR_CAP];
    __shared__ unsigned hist[BKT_W];
    __shared__ unsigned scanT[BKT_W];
    __shared__ unsigned cur[BKT_W];
    int b = blockIdx.x;
    int t = threadIdx.x;
    unsigned s = baseR[b], e_ = baseR[b + 1];
    int cnt = (int)(e_ - s);
    int node0 = b << LOG_BKT;
    if (t < BKT_W) hist[t] = 0u;
    __syncthreads();

    bool fast = (cnt <= CSR_CAP);
    if (fast) {
        for (int i = t; i < cnt; i += 256) {
            unsigned v = entries[s + i];
            ebuf[i] = v;
            atomicAdd(&hist[v >> 17], 1u);
        }
    } else {
        for (unsigned base = s; base < e_; base += CSR_CAP) {
            int cn = (int)(((e_ - base) < CSR_CAP) ? (e_ - base) : CSR_CAP);
            for (int i = t; i < cn; i += 256) atomicAdd(&hist[entries[base + i] >> 17], 1u);
        }
    }
    __syncthreads();
    if (t < BKT_W) scanT[t] = hist[t];
    __syncthreads();
    for (int d = 1; d < BKT_W; d <<= 1) {
        unsigned v = 0;
        if (t < BKT_W && t >= d) v = scanT[t - d];
        __syncthreads();
        if (t < BKT_W) scanT[t] += v;
        __syncthreads();
    }
    if (t < BKT_W) {
        unsigned excl = scanT[t] - hist[t];
        cur[t] = excl;
        int node = node0 + t;
        if (node <= N) nodeBeg[node] = s + excl;
    }
    __syncthreads();
    if (fast) {
        for (int i = t; i < cnt; i += 256) {
            unsigned v = ebuf[i];
            unsigned pos = atomicAdd(&cur[v >> 17], 1u);
            sbuf[pos] = v & 0x1FFFFu;
        }
        __syncthreads();
        for (int i = t; i < cnt; i += 256) entries[s + i] = sbuf[i];
    } else {
        if (t == 0) flags[b] = 1u;
    }
}

// per-node wave gather; entry list fetched lane-parallel, broadcast via shuffle,
// xs loads batched 8-wide (independent) to maximize memory-level parallelism.
template <bool PRESCALED>
__global__ void __launch_bounds__(256) k_gather(
        const float* __restrict__ x, const __half* __restrict__ xs,
        const float* __restrict__ dis, const unsigned* __restrict__ nodeBeg,
        const unsigned* __restrict__ baseR, const unsigned* __restrict__ flags,
        const unsigned* __restrict__ entries, float* __restrict__ out, int n) {
    int r = (blockIdx.x * blockDim.x + threadIdx.x) >> 6;
    int lane = threadIdx.x & 63;
    if (r >= n) return;
    float dr = dis[r];
    float acc = dr * x[(size_t)r * D_FEAT + lane];   // self term (final *dr below)
    int b = r >> LOG_BKT;
    if (!flags[b]) {
        unsigned s = nodeBeg[r], e_ = nodeBeg[r + 1];
        int cnt = (int)(e_ - s);
        for (int base = 0; base < cnt; base += 64) {
            int m = min(64, cnt - base);
            unsigned my_e = (lane < m) ? entries[s + base + lane] : 0u;
            int k = 0;
            for (; k + 8 <= m; k += 8) {
                unsigned c0 = __shfl(my_e, k),     c1 = __shfl(my_e, k + 1);
                unsigned c2 = __shfl(my_e, k + 2), c3 = __shfl(my_e, k + 3);
                unsigned c4 = __shfl(my_e, k + 4), c5 = __shfl(my_e, k + 5);
                unsigned c6 = __shfl(my_e, k + 6), c7 = __shfl(my_e, k + 7);
                if (PRESCALED) {
                    float v0 = __half2float(xs[(size_t)c0 * D_FEAT + lane]);
                    float v1 = __half2float(xs[(size_t)c1 * D_FEAT + lane]);
                    float v2 = __half2float(xs[(size_t)c2 * D_FEAT + lane]);
                    float v3 = __half2float(xs[(size_t)c3 * D_FEAT + lane]);
                    float v4 = __half2float(xs[(size_t)c4 * D_FEAT + lane]);
                    float v5 = __half2float(xs[(size_t)c5 * D_FEAT + lane]);
                    float v6 = __half2float(xs[(size_t)c6 * D_FEAT + lane]);
                    float v7 = __half2float(xs[(size_t)c7 * D_FEAT + lane]);
                    acc += ((v0 + v1) + (v2 + v3)) + ((v4 + v5) + (v6 + v7));
                } else {
                    float w0 = dis[c0], w1 = dis[c1], w2 = dis[c2], w3 = dis[c3];
                    float w4 = dis[c4], w5 = dis[c5], w6 = dis[c6], w7 = dis[c7];
                    float v0 = x[(size_t)c0 * D_FEAT + lane];
                    float v1 = x[(size_t)c1 * D_FEAT + lane];
                    float v2 = x[(size_t)c2 * D_FEAT + lane];
                    float v3 = x[(size_t)c3 * D_FEAT + lane];
                    float v4 = x[(size_t)c4 * D_FEAT + lane];
                    float v5 = x[(size_t)c5 * D_FEAT + lane];
                    float v6 = x[(size_t)c6 * D_FEAT + lane];
                    float v7 = x[(size_t)c7 * D_FEAT + lane];
                    acc = fmaf(w0, v0, acc); acc = fmaf(w1, v1, acc);
                    acc = fmaf(w2, v2, acc); acc = fmaf(w3, v3, acc);
                    acc = fmaf(w4, v4, acc); acc = fmaf(w5, v5, acc);
                    acc = fmaf(w6, v6, acc); acc = fmaf(w7, v7, acc);
                }
            }
            for (; k < m; ++k) {
                unsigned c = __shfl(my_e, k);
                if (PRESCALED) acc += __half2float(xs[(size_t)c * D_FEAT + lane]);
                else acc = fmaf(dis[c], x[(size_t)c * D_FEAT + lane], acc);
            }
        }
    } else {
        // rare overflow bucket: entries still tagged, filter-scan
        unsigned lr = (unsigned)(r & (BKT_W - 1));
        for (unsigned j = baseR[b]; j < baseR[b + 1]; ++j) {
            unsigned v = entries[j];
            if ((v >> 17) == lr) {
                unsigned c = v & 0x1FFFFu;
                if (PRESCALED) acc += __half2float(xs[(size_t)c * D_FEAT + lane]);
                else acc = fmaf(dis[c], x[(size_t)c * D_FEAT + lane], acc);
            }
        }
    }
    out[(size_t)r * D_FEAT + lane] = dr * acc;
}

// ---------------- fallback path (round-1 atomic scatter) ----------------

__global__ void k_init_deg(float* __restrict__ deg, int n) {
    int i = blockIdx.x * blockDim.x + threadIdx.x;
    if (i < n) deg[i] = 1.0f;
}
__global__ void k_count_deg(const int* __restrict__ col, float* __restrict__ deg, int E) {
    int e = blockIdx.x * blockDim.x + threadIdx.x;
    if (e < E) atomicAdd(&deg[col[e]], 1.0f);
}
__global__ void k_deg_to_dis(float* __restrict__ deg, int n) {
    int i = blockIdx.x * blockDim.x + threadIdx.x;
    if (i < n) deg[i] = rsqrtf(deg[i]);
}
__global__ void k_self_init(const float* __restrict__ x, const float* __restrict__ dis,
                            float* __restrict__ out, int total) {
    int idx = blockIdx.x * blockDim.x + threadIdx.x;
    if (idx < total) {
        int node = idx >> 6;
        float s = dis[node];
        out[idx] = s * s * x[idx];
    }
}
__global__ void k_scatter(const int* __restrict__ row, const int* __restrict__ col,
                          const float* __restrict__ x, const float* __restrict__ dis,
                          float* __restrict__ out, int E) {
    int gtid = blockIdx.x * blockDim.x + threadIdx.x;
    int edge = gtid >> 6;
    int lane = threadIdx.x & 63;
    if (edge < E) {
        int r = row[edge];
        int c = col[edge];
        float nrm = dis[r] * dis[c];
        atomicAdd(&out[r * D_FEAT + lane], nrm * x[c * D_FEAT + lane]);
    }
}

extern "C" void kernel_launch(void* const* d_in, const int* in_sizes, int n_in,
                              void* d_out, int out_size, void* d_ws, size_t ws_size,
                              hipStream_t stream) {
    const float* x = (const float*)d_in[0];
    const int* ei = (const int*)d_in[1];

    const int N = in_sizes[0] / D_FEAT;   // 100000
    const int E = in_sizes[1] / 2;        // 1000000
    const int* row = ei;
    const int* col = ei + E;

    float* out = (float*)d_out;
    const int B = 256;
    const int nBkt = (N + BKT_W - 1) >> LOG_BKT;

    // ws words: dis[N] | baseR[1025] | baseC[1025] | cursorR[1024] | cursorC[1024]
    //           | histRC[2048] | flags[1024] | nodeBeg[N+1] | entries[E] | tail
    size_t words = (size_t)2 * N + (size_t)E + 7171;
    size_t tailFast = (size_t)N * D_FEAT * 2;               // xs (fp16); colslab overlays it
    if (tailFast < (size_t)E) tailFast = (size_t)E;
    size_t needFast = words * 4 + tailFast;
    size_t needMid  = words * 4 + (size_t)E;                // colslab only, gather from f32 x

    if (N <= 131072 && nBkt <= 1024 && ws_size >= needMid) {
        bool pre = (ws_size >= needFast);
        float*    dis     = (float*)d_ws;
        unsigned* baseR   = (unsigned*)(dis + N);
        unsigned* baseC   = baseR + 1025;
        unsigned* cursorR = baseC + 1025;
        unsigned* cursorC = cursorR + 1024;
        unsigned* histRC  = cursorC + 1024;
        unsigned* flags   = histRC + 2048;
        unsigned* nodeBeg = flags + 1024;
        unsigned* entries = nodeBeg + (N + 1);
        unsigned char* colslab = (unsigned char*)(entries + E);
        __half*   xs      = (__half*)(entries + E);         // overlays colslab (used after)

        k_zero<<<8, B, 0, stream>>>(histRC, flags);
        k_hist2<<<(E + HIST_CHUNK - 1) / HIST_CHUNK, B, 0, stream>>>(row, col, histRC, E);
        k_scan<<<2, B, 0, stream>>>(histRC, baseR, baseC, cursorR, cursorC, nodeBeg, E, N);
        k_part2<<<(E + PART_CHUNK - 1) / PART_CHUNK, B, 0, stream>>>(
            row, col, cursorR, cursorC, entries, colslab, E);
        k_colcount<<<nBkt, B, 0, stream>>>(colslab, baseC, dis, N);   // consumes colslab
        k_localcsr<<<nBkt, B, 0, stream>>>(entries, baseR, nodeBeg, flags, N);
        if (pre) {
            k_scale<<<(N * (D_FEAT / 4) + B - 1) / B, B, 0, stream>>>(x, dis, xs, N);  // overwrites colslab
        }

        long long gthreads = (long long)N * 64;
        int gblocks = (int)((gthreads + B - 1) / B);
        if (pre)
            k_gather<true><<<gblocks, B, 0, stream>>>(x, xs, dis, nodeBeg, baseR, flags, entries, out, N);
        else
            k_gather<false><<<gblocks, B, 0, stream>>>(x, xs, dis, nodeBeg, baseR, flags, entries, out, N);
    } else {
        // fallback: atomic scatter (needs only N floats of ws)
        float* deg = (float*)d_ws;
        k_init_deg<<<(N + B - 1) / B, B, 0, stream>>>(deg, N);
        k_count_deg<<<(E + B - 1) / B, B, 0, stream>>>(col, deg, E);
        k_deg_to_dis<<<(N + B - 1) / B, B, 0, stream>>>(deg, N);
        int total = N * D_FEAT;
        k_self_init<<<(total + B - 1) / B, B, 0, stream>>>(x, deg, out, total);
        long long st = (long long)E * 64;
        k_scatter<<<(int)((st + B - 1) / B), B, 0, stream>>>(row, col, x, deg, out, E);
    }
}

// Round 6
// 131.483 us; speedup vs baseline: 4.2469x; 1.2236x over previous
//
#include <hip/hip_runtime.h>
#include <hip/hip_fp16.h>

#define D_FEAT 64
#define LOG_BKT 9
#define BKT_W 512            // nodes per bucket
#define NBIN 256             // max buckets (N <= 131072)
#define CHUNK 2048           // edges per WG in hist/part (489 WGs at E=1M)

// ---------------- fast path ----------------

// zero histRC[512]
__global__ void k_zero(unsigned* __restrict__ histRC) {
    int i = blockIdx.x * blockDim.x + threadIdx.x;
    if (i < 2 * NBIN) histRC[i] = 0u;
}

// LDS-privatized coarse hist: row>>9 -> bins 0..255, col>>9 -> bins 256..511
__global__ void k_hist2(const int* __restrict__ row, const int* __restrict__ col,
                        unsigned* __restrict__ histRC, int E) {
    __shared__ unsigned h[2 * NBIN];
    int t = threadIdx.x;
    h[t] = 0u; h[t + 256] = 0u;
    __syncthreads();
    long long c0 = (long long)blockIdx.x * CHUNK;
    for (int k = 0; k < CHUNK / 256; ++k) {
        long long e = c0 + (long long)k * 256 + t;
        if (e < E) {
            atomicAdd(&h[row[e] >> LOG_BKT], 1u);
            atomicAdd(&h[NBIN + (col[e] >> LOG_BKT)], 1u);
        }
    }
    __syncthreads();
    unsigned c = h[t];       if (c) atomicAdd(&histRC[t], c);
    c = h[t + 256];          if (c) atomicAdd(&histRC[t + 256], c);
}

// grid=2: block 0 scans row bins -> baseR/cursorR; block 1 col bins -> baseC/cursorC
__global__ void k_scan(const unsigned* __restrict__ histRC,
                       unsigned* __restrict__ baseR, unsigned* __restrict__ baseC,
                       unsigned* __restrict__ cursorR, unsigned* __restrict__ cursorC,
                       unsigned* __restrict__ nodeBeg, int E, int N) {
    __shared__ unsigned lds[256];
    const unsigned* hist = histRC + (size_t)blockIdx.x * NBIN;
    unsigned* base = blockIdx.x ? baseC : baseR;
    unsigned* cur  = blockIdx.x ? cursorC : cursorR;
    int t = threadIdx.x;
    unsigned v = hist[t];
    lds[t] = v;
    __syncthreads();
    for (int d = 1; d < 256; d <<= 1) {
        unsigned a = (t >= d) ? lds[t - d] : 0u;
        __syncthreads();
        lds[t] += a;
        __syncthreads();
    }
    unsigned excl = lds[t] - v;
    base[t] = excl; cur[t] = excl;
    if (t == 255) {
        base[256] = (unsigned)E;
        if (blockIdx.x == 0) nodeBeg[N] = (unsigned)E;
    }
}

// fused partition: row-entries (4B: (row&511)<<17|col) and col-u16 (col&511)
__global__ void k_part2(const int* __restrict__ row, const int* __restrict__ col,
                        unsigned* __restrict__ cursorR, unsigned* __restrict__ cursorC,
                        unsigned* __restrict__ entries, unsigned short* __restrict__ colslab,
                        int E) {
    __shared__ unsigned ldsR[NBIN];
    __shared__ unsigned ldsC[NBIN];
    int t = threadIdx.x;
    ldsR[t] = 0u; ldsC[t] = 0u;
    __syncthreads();
    long long c0 = (long long)blockIdx.x * CHUNK;
    for (int k = 0; k < CHUNK / 256; ++k) {
        long long e = c0 + (long long)k * 256 + t;
        if (e < E) {
            atomicAdd(&ldsR[row[e] >> LOG_BKT], 1u);
            atomicAdd(&ldsC[col[e] >> LOG_BKT], 1u);
        }
    }
    __syncthreads();
    unsigned c = ldsR[t]; ldsR[t] = c ? atomicAdd(&cursorR[t], c) : 0u;
    c = ldsC[t];          ldsC[t] = c ? atomicAdd(&cursorC[t], c) : 0u;
    __syncthreads();
    for (int k = 0; k < CHUNK / 256; ++k) {
        long long e = c0 + (long long)k * 256 + t;
        if (e < E) {
            int r = row[e], cc = col[e];
            unsigned pr = atomicAdd(&ldsR[r >> LOG_BKT], 1u);
            entries[pr] = ((unsigned)(r & (BKT_W - 1)) << 17) | (unsigned)cc;
            unsigned pc = atomicAdd(&ldsC[cc >> LOG_BKT], 1u);
            colslab[pc] = (unsigned short)(cc & (BKT_W - 1));
        }
    }
}

// one WG per col-bucket: count local col ids -> dis[node] = rsqrt(cnt+1)
__global__ void k_colcount(const unsigned short* __restrict__ colslab,
                           const unsigned* __restrict__ baseC,
                           float* __restrict__ dis, int N) {
    __shared__ unsigned h[BKT_W];
    int b = blockIdx.x, t = threadIdx.x;
    h[t] = 0u; h[t + 256] = 0u;
    __syncthreads();
    unsigned s = baseC[b], e_ = baseC[b + 1];
    for (unsigned i = s + t; i < e_; i += 256) atomicAdd(&h[colslab[i]], 1u);
    __syncthreads();
    int node0 = b << LOG_BKT;
    int n0 = node0 + t, n1 = node0 + t + 256;
    if (n0 < N) dis[n0] = rsqrtf((float)(h[t] + 1u));
    if (n1 < N) dis[n1] = rsqrtf((float)(h[t + 256] + 1u));
}

// one WG per row-bucket: per-node counts (global reread), LDS scan, place
// col-only values into sorted[]; emit nodeBeg. No caps, no overflow path.
__global__ void __launch_bounds__(256) k_localcsr(
        const unsigned* __restrict__ entries, unsigned* __restrict__ sorted,
        const unsigned* __restrict__ baseR, unsigned* __restrict__ nodeBeg, int N) {
    __shared__ unsigned hist[BKT_W];
    __shared__ unsigned cur[BKT_W];
    __shared__ unsigned scanT[256];
    int b = blockIdx.x, t = threadIdx.x;
    hist[t] = 0u; hist[t + 256] = 0u;
    __syncthreads();
    unsigned s = baseR[b], e_ = baseR[b + 1];
    int cnt = (int)(e_ - s);
    for (int i = t; i < cnt; i += 256) atomicAdd(&hist[entries[s + i] >> 17], 1u);
    __syncthreads();
    unsigned a = hist[2 * t], bb = hist[2 * t + 1], s2 = a + bb;
    scanT[t] = s2;
    __syncthreads();
    for (int d = 1; d < 256; d <<= 1) {
        unsigned ad = (t >= d) ? scanT[t - d] : 0u;
        __syncthreads();
        scanT[t] += ad;
        __syncthreads();
    }
    unsigned excl = scanT[t] - s2;
    cur[2 * t] = excl; cur[2 * t + 1] = excl + a;
    int node0 = b << LOG_BKT;
    int n0 = node0 + 2 * t, n1 = n0 + 1;
    if (n0 < N) nodeBeg[n0] = s + excl;
    if (n1 < N) nodeBeg[n1] = s + excl + a;
    __syncthreads();
    for (int i = t; i < cnt; i += 256) {
        unsigned v = entries[s + i];
        unsigned pos = atomicAdd(&cur[v >> 17], 1u);
        sorted[s + pos] = v & 0x1FFFFu;
    }
}

// xs = dis * x, fp16
__global__ void k_scale(const float* __restrict__ x, const float* __restrict__ dis,
                        __half* __restrict__ xs, int N) {
    int i = blockIdx.x * blockDim.x + threadIdx.x;
    if (i >= N * (D_FEAT / 4)) return;
    int node = i >> 4;
    float d = dis[node];
    float4 v = ((const float4*)x)[i];
    __half2 p0 = __floats2half2_rn(d * v.x, d * v.y);
    __half2 p1 = __floats2half2_rn(d * v.z, d * v.w);
    ((__half2*)xs)[i * 2]     = p0;
    ((__half2*)xs)[i * 2 + 1] = p1;
}

// per-node wave gather, dual-column: lane-group g in {0,1}; lane owns feats (2m,2m+1)
// as float2; group 0 takes even-position cols, group 1 odd; combine via shfl xor 32.
// Each half2 load instruction moves 256B/wave = 2 full fp16 rows.
template <bool PRE>
__global__ void __launch_bounds__(256) k_gather(
        const float* __restrict__ x, const __half* __restrict__ xs,
        const float* __restrict__ dis, const unsigned* __restrict__ nodeBeg,
        const unsigned* __restrict__ sorted, float* __restrict__ out, int n) {
    int r = (blockIdx.x * blockDim.x + threadIdx.x) >> 6;
    int lane = threadIdx.x & 63;
    if (r >= n) return;
    int g = lane >> 5, m = lane & 31;
    float dr = dis[r];
    float2 acc;
    if (g == 0) {
        float2 xv = ((const float2*)x)[(size_t)r * 32 + m];
        acc.x = dr * xv.x; acc.y = dr * xv.y;          // self term (final *dr below)
    } else {
        acc.x = 0.f; acc.y = 0.f;
    }
    unsigned s = nodeBeg[r], e_ = nodeBeg[r + 1];
    int cnt = (int)(e_ - s);
    const __half2* xs2 = (const __half2*)xs;
    for (int base = 0; base < cnt; base += 64) {
        int mm = min(64, cnt - base);
        unsigned my_e = (lane < mm) ? sorted[s + base + lane] : 0u;
        int k = 0;
        for (; k + 8 <= mm; k += 8) {
            unsigned c0 = __shfl(my_e, k + g),     c1 = __shfl(my_e, k + 2 + g);
            unsigned c2 = __shfl(my_e, k + 4 + g), c3 = __shfl(my_e, k + 6 + g);
            if (PRE) {
                float2 f0 = __half22float2(xs2[(size_t)c0 * 32 + m]);
                float2 f1 = __half22float2(xs2[(size_t)c1 * 32 + m]);
                float2 f2 = __half22float2(xs2[(size_t)c2 * 32 + m]);
                float2 f3 = __half22float2(xs2[(size_t)c3 * 32 + m]);
                acc.x += (f0.x + f1.x) + (f2.x + f3.x);
                acc.y += (f0.y + f1.y) + (f2.y + f3.y);
            } else {
                float w0 = dis[c0], w1 = dis[c1], w2 = dis[c2], w3 = dis[c3];
                float2 f0 = ((const float2*)x)[(size_t)c0 * 32 + m];
                float2 f1 = ((const float2*)x)[(size_t)c1 * 32 + m];
                float2 f2 = ((const float2*)x)[(size_t)c2 * 32 + m];
                float2 f3 = ((const float2*)x)[(size_t)c3 * 32 + m];
                acc.x = fmaf(w0, f0.x, acc.x); acc.y = fmaf(w0, f0.y, acc.y);
                acc.x = fmaf(w1, f1.x, acc.x); acc.y = fmaf(w1, f1.y, acc.y);
                acc.x = fmaf(w2, f2.x, acc.x); acc.y = fmaf(w2, f2.y, acc.y);
                acc.x = fmaf(w3, f3.x, acc.x); acc.y = fmaf(w3, f3.y, acc.y);
            }
        }
        for (; k < mm; k += 2) {
            if (k + g < mm) {
                unsigned c = __shfl(my_e, k + g);
                if (PRE) {
                    float2 f = __half22float2(xs2[(size_t)c * 32 + m]);
                    acc.x += f.x; acc.y += f.y;
                } else {
                    float w = dis[c];
                    float2 f = ((const float2*)x)[(size_t)c * 32 + m];
                    acc.x = fmaf(w, f.x, acc.x); acc.y = fmaf(w, f.y, acc.y);
                }
            }
        }
    }
    acc.x += __shfl(acc.x, lane ^ 32);
    acc.y += __shfl(acc.y, lane ^ 32);
    if (g == 0) {
        float2 o; o.x = dr * acc.x; o.y = dr * acc.y;
        ((float2*)out)[(size_t)r * 32 + m] = o;
    }
}

// ---------------- fallback path (round-1 atomic scatter) ----------------

__global__ void k_init_deg(float* __restrict__ deg, int n) {
    int i = blockIdx.x * blockDim.x + threadIdx.x;
    if (i < n) deg[i] = 1.0f;
}
__global__ void k_count_deg(const int* __restrict__ col, float* __restrict__ deg, int E) {
    int e = blockIdx.x * blockDim.x + threadIdx.x;
    if (e < E) atomicAdd(&deg[col[e]], 1.0f);
}
__global__ void k_deg_to_dis(float* __restrict__ deg, int n) {
    int i = blockIdx.x * blockDim.x + threadIdx.x;
    if (i < n) deg[i] = rsqrtf(deg[i]);
}
__global__ void k_self_init(const float* __restrict__ x, const float* __restrict__ dis,
                            float* __restrict__ out, int total) {
    int idx = blockIdx.x * blockDim.x + threadIdx.x;
    if (idx < total) {
        int node = idx >> 6;
        float s = dis[node];
        out[idx] = s * s * x[idx];
    }
}
__global__ void k_scatter(const int* __restrict__ row, const int* __restrict__ col,
                          const float* __restrict__ x, const float* __restrict__ dis,
                          float* __restrict__ out, int E) {
    int gtid = blockIdx.x * blockDim.x + threadIdx.x;
    int edge = gtid >> 6;
    int lane = threadIdx.x & 63;
    if (edge < E) {
        int r = row[edge];
        int c = col[edge];
        float nrm = dis[r] * dis[c];
        atomicAdd(&out[r * D_FEAT + lane], nrm * x[c * D_FEAT + lane]);
    }
}

extern "C" void kernel_launch(void* const* d_in, const int* in_sizes, int n_in,
                              void* d_out, int out_size, void* d_ws, size_t ws_size,
                              hipStream_t stream) {
    const float* x = (const float*)d_in[0];
    const int* ei = (const int*)d_in[1];

    const int N = in_sizes[0] / D_FEAT;   // 100000
    const int E = in_sizes[1] / 2;        // 1000000
    const int* row = ei;
    const int* col = ei + E;

    float* out = (float*)d_out;
    const int B = 256;
    const int nBkt = (N + BKT_W - 1) >> LOG_BKT;

    // ws words: dis[N] | baseR[257] | baseC[257] | cursorR[256] | cursorC[256]
    //           | histRC[512] | nodeBeg[N+1] | sorted[E] | tail
    // tail holds entries[E] (4B) + colslab[E] (2B), later overlaid by xs (N*128 B)
    size_t words = (size_t)2 * N + (size_t)E + 1539;
    size_t tailEC   = (size_t)E * 6;                  // entries + colslab
    size_t tailFast = (size_t)N * D_FEAT * 2;         // xs
    size_t tailMax  = tailEC > tailFast ? tailEC : tailFast;
    size_t needFast = words * 4 + tailMax;
    size_t needMid  = words * 4 + tailEC;

    if (N <= 131072 && nBkt <= NBIN && ws_size >= needMid) {
        bool pre = (ws_size >= needFast);
        float*    dis     = (float*)d_ws;
        unsigned* baseR   = (unsigned*)(dis + N);
        unsigned* baseC   = baseR + 257;
        unsigned* cursorR = baseC + 257;
        unsigned* cursorC = cursorR + 256;
        unsigned* histRC  = cursorC + 256;
        unsigned* nodeBeg = histRC + 512;
        unsigned* sorted  = nodeBeg + (N + 1);
        unsigned* entries = sorted + E;
        unsigned short* colslab = (unsigned short*)(entries + E);
        __half*   xs      = (__half*)entries;          // overlays entries+colslab after localcsr

        int nWG = (E + CHUNK - 1) / CHUNK;             // 489

        k_zero<<<2, B, 0, stream>>>(histRC);
        k_hist2<<<nWG, B, 0, stream>>>(row, col, histRC, E);
        k_scan<<<2, B, 0, stream>>>(histRC, baseR, baseC, cursorR, cursorC, nodeBeg, E, N);
        k_part2<<<nWG, B, 0, stream>>>(row, col, cursorR, cursorC, entries, colslab, E);
        k_colcount<<<nBkt, B, 0, stream>>>(colslab, baseC, dis, N);
        k_localcsr<<<nBkt, B, 0, stream>>>(entries, sorted, baseR, nodeBeg, N);
        if (pre) {
            k_scale<<<(N * (D_FEAT / 4) + B - 1) / B, B, 0, stream>>>(x, dis, xs, N);
        }
        long long gthreads = (long long)N * 64;
        int gblocks = (int)((gthreads + B - 1) / B);
        if (pre)
            k_gather<true><<<gblocks, B, 0, stream>>>(x, xs, dis, nodeBeg, sorted, out, N);
        else
            k_gather<false><<<gblocks, B, 0, stream>>>(x, xs, dis, nodeBeg, sorted, out, N);
    } else {
        // fallback: atomic scatter (needs only N floats of ws)
        float* deg = (float*)d_ws;
        k_init_deg<<<(N + B - 1) / B, B, 0, stream>>>(deg, N);
        k_count_deg<<<(E + B - 1) / B, B, 0, stream>>>(col, deg, E);
        k_deg_to_dis<<<(N + B - 1) / B, B, 0, stream>>>(deg, N);
        int total = N * D_FEAT;
        k_self_init<<<(total + B - 1) / B, B, 0, stream>>>(x, deg, out, total);
        long long st = (long long)E * 64;
        k_scatter<<<(int)((st + B - 1) / B), B, 0, stream>>>(row, col, x, deg, out, E);
    }
}

// Round 8
// 100.397 us; speedup vs baseline: 5.5619x; 1.3096x over previous
//
#include <hip/hip_runtime.h>
#include <hip/hip_fp16.h>

#define D_FEAT 64
#define LOG_BKT 9
#define BKT_W 512            // nodes per bucket
#define NBIN 256             // bins (N <= 131072)
#define CHUNK 2048           // edges per WG in histdump/part (489 WGs at E=1M)

// ---------------- fast path ----------------

// per-WG 512-bin histogram (row bins 0..255, col bins 256..511) -> global slab.
// Plain stores: no zeroing kernel, no global atomics.
__global__ void k_histdump(const int* __restrict__ row, const int* __restrict__ col,
                           unsigned* __restrict__ wgHist, int E) {
    __shared__ unsigned h[512];
    int t = threadIdx.x;
    h[t] = 0u; h[t + 256] = 0u;
    __syncthreads();
    long long c0 = (long long)blockIdx.x * CHUNK;
    for (int k = 0; k < CHUNK / 256; ++k) {
        long long e = c0 + (long long)k * 256 + t;
        if (e < E) {
            atomicAdd(&h[row[e] >> LOG_BKT], 1u);
            atomicAdd(&h[256 + (col[e] >> LOG_BKT)], 1u);
        }
    }
    __syncthreads();
    unsigned* dst = wgHist + (size_t)blockIdx.x * 512;
    dst[t] = h[t]; dst[t + 256] = h[t + 256];
}

// one block per bin: exclusive prefix over WGs (in-place cursors), total -> binTot.
// WG pair order (t, t+256) is arbitrary but fixed: ranges are disjoint and tile.
__global__ void k_scan2a(unsigned* __restrict__ wgHist, unsigned* __restrict__ binTot,
                         int nWG) {
    __shared__ unsigned lds[256];
    int b = blockIdx.x, t = threadIdx.x;
    unsigned v0 = (t < nWG) ? wgHist[(size_t)t * 512 + b] : 0u;
    unsigned v1 = (t + 256 < nWG) ? wgHist[(size_t)(t + 256) * 512 + b] : 0u;
    unsigned s = v0 + v1;
    lds[t] = s;
    __syncthreads();
    for (int d = 1; d < 256; d <<= 1) {
        unsigned a = (t >= d) ? lds[t - d] : 0u;
        __syncthreads();
        lds[t] += a;
        __syncthreads();
    }
    unsigned excl = lds[t] - s;
    if (t < nWG) wgHist[(size_t)t * 512 + b] = excl;
    if (t + 256 < nWG) wgHist[(size_t)(t + 256) * 512 + b] = excl + v0;
    if (t == 255) binTot[b] = lds[255];
}

// single block: scan row-bin totals -> baseR[257], col-bin totals -> baseC[257].
__global__ void k_scan2b(const unsigned* __restrict__ binTot,
                         unsigned* __restrict__ baseR, unsigned* __restrict__ baseC,
                         unsigned* __restrict__ nodeBeg, int E, int N) {
    __shared__ unsigned lds[256];
    int t = threadIdx.x;
    unsigned v = binTot[t];
    lds[t] = v;
    __syncthreads();
    for (int d = 1; d < 256; d <<= 1) {
        unsigned a = (t >= d) ? lds[t - d] : 0u;
        __syncthreads();
        lds[t] += a;
        __syncthreads();
    }
    baseR[t] = lds[t] - v;
    if (t == 255) baseR[256] = (unsigned)E;
    __syncthreads();
    unsigned w = binTot[256 + t];
    lds[t] = w;
    __syncthreads();
    for (int d = 1; d < 256; d <<= 1) {
        unsigned a = (t >= d) ? lds[t - d] : 0u;
        __syncthreads();
        lds[t] += a;
        __syncthreads();
    }
    baseC[t] = lds[t] - w;
    if (t == 255) baseC[256] = (unsigned)E;
    if (t == 0) nodeBeg[N] = (unsigned)E;   // sentinel
}

// single placement pass: cursors preloaded from slab, only LDS atomics.
__global__ void k_part2(const int* __restrict__ row, const int* __restrict__ col,
                        const unsigned* __restrict__ wgHist,
                        const unsigned* __restrict__ baseR, const unsigned* __restrict__ baseC,
                        unsigned* __restrict__ entries, unsigned short* __restrict__ colslab,
                        int E) {
    __shared__ unsigned cR[256];
    __shared__ unsigned cC[256];
    int t = threadIdx.x;
    const unsigned* my = wgHist + (size_t)blockIdx.x * 512;
    cR[t] = my[t] + baseR[t];
    cC[t] = my[t + 256] + baseC[t];
    __syncthreads();
    long long c0 = (long long)blockIdx.x * CHUNK;
    for (int k = 0; k < CHUNK / 256; ++k) {
        long long e = c0 + (long long)k * 256 + t;
        if (e < E) {
            int r = row[e], cc = col[e];
            unsigned pr = atomicAdd(&cR[r >> LOG_BKT], 1u);
            entries[pr] = ((unsigned)(r & (BKT_W - 1)) << 17) | (unsigned)cc;
            unsigned pc = atomicAdd(&cC[cc >> LOG_BKT], 1u);
            colslab[pc] = (unsigned short)(cc & (BKT_W - 1));
        }
    }
}

// fused independent mid-work: blocks [0,nBkt) do colcount (dis), [nBkt,2nBkt) localcsr.
__global__ void __launch_bounds__(256) k_mid(
        const unsigned* __restrict__ entries, unsigned* __restrict__ sorted,
        const unsigned* __restrict__ baseR, unsigned* __restrict__ nodeBeg,
        const unsigned short* __restrict__ colslab, const unsigned* __restrict__ baseC,
        float* __restrict__ dis, int N, int nBkt) {
    __shared__ unsigned shA[512];   // hist
    __shared__ unsigned shB[512];   // cur
    __shared__ unsigned shC[256];   // scan temp
    int b = blockIdx.x, t = threadIdx.x;
    if (b < nBkt) {
        // ---- colcount: dis[node] = rsqrt(cnt+1) ----
        shA[t] = 0u; shA[t + 256] = 0u;
        __syncthreads();
        unsigned s = baseC[b], e_ = baseC[b + 1];
        for (unsigned i = s + t; i < e_; i += 256) atomicAdd(&shA[colslab[i]], 1u);
        __syncthreads();
        int node0 = b << LOG_BKT;
        int n0 = node0 + t, n1 = node0 + t + 256;
        if (n0 < N) dis[n0] = rsqrtf((float)(shA[t] + 1u));
        if (n1 < N) dis[n1] = rsqrtf((float)(shA[t + 256] + 1u));
    } else {
        // ---- localcsr: per-node CSR within bucket ----
        b -= nBkt;
        shA[t] = 0u; shA[t + 256] = 0u;
        __syncthreads();
        unsigned s = baseR[b], e_ = baseR[b + 1];
        int cnt = (int)(e_ - s);
        for (int i = t; i < cnt; i += 256) atomicAdd(&shA[entries[s + i] >> 17], 1u);
        __syncthreads();
        unsigned a = shA[2 * t], bb = shA[2 * t + 1], s2 = a + bb;
        shC[t] = s2;
        __syncthreads();
        for (int d = 1; d < 256; d <<= 1) {
            unsigned ad = (t >= d) ? shC[t - d] : 0u;
            __syncthreads();
            shC[t] += ad;
            __syncthreads();
        }
        unsigned excl = shC[t] - s2;
        shB[2 * t] = excl; shB[2 * t + 1] = excl + a;
        int node0 = b << LOG_BKT;
        int n0 = node0 + 2 * t, n1 = n0 + 1;
        if (n0 < N) nodeBeg[n0] = s + excl;
        if (n1 < N) nodeBeg[n1] = s + excl + a;
        __syncthreads();
        for (int i = t; i < cnt; i += 256) {
            unsigned v = entries[s + i];
            unsigned pos = atomicAdd(&shB[v >> 17], 1u);
            sorted[s + pos] = v & 0x1FFFFu;
        }
    }
}

// xs = dis * x, fp16
__global__ void k_scale(const float* __restrict__ x, const float* __restrict__ dis,
                        __half* __restrict__ xs, int N) {
    int i = blockIdx.x * blockDim.x + threadIdx.x;
    if (i >= N * (D_FEAT / 4)) return;
    int node = i >> 4;
    float d = dis[node];
    float4 v = ((const float4*)x)[i];
    __half2 p0 = __floats2half2_rn(d * v.x, d * v.y);
    __half2 p1 = __floats2half2_rn(d * v.z, d * v.w);
    ((__half2*)xs)[i * 2]     = p0;
    ((__half2*)xs)[i * 2 + 1] = p1;
}

// per-node wave gather (round-6 proven version): 2 groups x 32 lanes, lane owns
// feats (2m,2m+1); group 0 even-position cols, group 1 odd; __half2 4B loads;
// f32 self term from x; combine via shfl(lane^32).
__global__ void __launch_bounds__(256) k_gather(
        const float* __restrict__ x, const __half* __restrict__ xs,
        const float* __restrict__ dis, const unsigned* __restrict__ nodeBeg,
        const unsigned* __restrict__ sorted, float* __restrict__ out, int n) {
    int r = (blockIdx.x * blockDim.x + threadIdx.x) >> 6;
    int lane = threadIdx.x & 63;
    if (r >= n) return;
    int g = lane >> 5, m = lane & 31;
    float dr = dis[r];
    float2 acc;
    if (g == 0) {
        float2 xv = ((const float2*)x)[(size_t)r * 32 + m];
        acc.x = dr * xv.x; acc.y = dr * xv.y;          // self term (final *dr below)
    } else {
        acc.x = 0.f; acc.y = 0.f;
    }
    unsigned s = nodeBeg[r], e_ = nodeBeg[r + 1];
    int cnt = (int)(e_ - s);
    const __half2* xs2 = (const __half2*)xs;
    for (int base = 0; base < cnt; base += 64) {
        int mm = min(64, cnt - base);
        unsigned my_e = (lane < mm) ? sorted[s + base + lane] : 0u;
        int k = 0;
        for (; k + 8 <= mm; k += 8) {
            unsigned c0 = __shfl(my_e, k + g),     c1 = __shfl(my_e, k + 2 + g);
            unsigned c2 = __shfl(my_e, k + 4 + g), c3 = __shfl(my_e, k + 6 + g);
            float2 f0 = __half22float2(xs2[(size_t)c0 * 32 + m]);
            float2 f1 = __half22float2(xs2[(size_t)c1 * 32 + m]);
            float2 f2 = __half22float2(xs2[(size_t)c2 * 32 + m]);
            float2 f3 = __half22float2(xs2[(size_t)c3 * 32 + m]);
            acc.x += (f0.x + f1.x) + (f2.x + f3.x);
            acc.y += (f0.y + f1.y) + (f2.y + f3.y);
        }
        for (; k < mm; k += 2) {
            if (k + g < mm) {
                unsigned c = __shfl(my_e, k + g);
                float2 f = __half22float2(xs2[(size_t)c * 32 + m]);
                acc.x += f.x; acc.y += f.y;
            }
        }
    }
    acc.x += __shfl(acc.x, lane ^ 32);
    acc.y += __shfl(acc.y, lane ^ 32);
    if (g == 0) {
        float2 o; o.x = dr * acc.x; o.y = dr * acc.y;
        ((float2*)out)[(size_t)r * 32 + m] = o;
    }
}

// ---------------- fallback path (round-1 atomic scatter) ----------------

__global__ void k_init_deg(float* __restrict__ deg, int n) {
    int i = blockIdx.x * blockDim.x + threadIdx.x;
    if (i < n) deg[i] = 1.0f;
}
__global__ void k_count_deg(const int* __restrict__ col, float* __restrict__ deg, int E) {
    int e = blockIdx.x * blockDim.x + threadIdx.x;
    if (e < E) atomicAdd(&deg[col[e]], 1.0f);
}
__global__ void k_deg_to_dis(float* __restrict__ deg, int n) {
    int i = blockIdx.x * blockDim.x + threadIdx.x;
    if (i < n) deg[i] = rsqrtf(deg[i]);
}
__global__ void k_self_init(const float* __restrict__ x, const float* __restrict__ dis,
                            float* __restrict__ out, int total) {
    int idx = blockIdx.x * blockDim.x + threadIdx.x;
    if (idx < total) {
        int node = idx >> 6;
        float s = dis[node];
        out[idx] = s * s * x[idx];
    }
}
__global__ void k_scatter(const int* __restrict__ row, const int* __restrict__ col,
                          const float* __restrict__ x, const float* __restrict__ dis,
                          float* __restrict__ out, int E) {
    int gtid = blockIdx.x * blockDim.x + threadIdx.x;
    int edge = gtid >> 6;
    int lane = threadIdx.x & 63;
    if (edge < E) {
        int r = row[edge];
        int c = col[edge];
        float nrm = dis[r] * dis[c];
        atomicAdd(&out[r * D_FEAT + lane], nrm * x[c * D_FEAT + lane]);
    }
}

extern "C" void kernel_launch(void* const* d_in, const int* in_sizes, int n_in,
                              void* d_out, int out_size, void* d_ws, size_t ws_size,
                              hipStream_t stream) {
    const float* x = (const float*)d_in[0];
    const int* ei = (const int*)d_in[1];

    const int N = in_sizes[0] / D_FEAT;   // 100000
    const int E = in_sizes[1] / 2;        // 1000000
    const int* row = ei;
    const int* col = ei + E;

    float* out = (float*)d_out;
    const int B = 256;
    const int nBkt = (N + BKT_W - 1) >> LOG_BKT;
    const int nWG = (E + CHUNK - 1) / CHUNK;

    // ws words: dis[N] | baseR[257] | baseC[257] | binTot[512] | nodeBeg[N+1] | pad
    //           | sorted[E] (wgHist[nWG*512] overlays its head until part2)
    //           | tail: max(entries[E]*4 + colslab[E]*2, xs N*128B)
    size_t preSorted = (size_t)N + 257 + 257 + 512 + (size_t)(N + 1);
    preSorted = (preSorted + 3) & ~(size_t)3;       // 16B-align sorted/entries/xs
    size_t tailBytes = (size_t)E * 6;
    size_t xsBytes = (size_t)N * D_FEAT * 2;
    if (xsBytes > tailBytes) tailBytes = xsBytes;
    size_t need = (preSorted + (size_t)E) * 4 + tailBytes;

    if (N <= 131072 && nBkt <= NBIN && nWG <= 512 &&
        (size_t)nWG * 512 <= (size_t)E && ws_size >= need) {
        float*    dis     = (float*)d_ws;
        unsigned* baseR   = (unsigned*)(dis + N);
        unsigned* baseC   = baseR + 257;
        unsigned* binTot  = baseC + 257;
        unsigned* nodeBeg = binTot + 512;
        unsigned* sorted  = (unsigned*)d_ws + preSorted;
        unsigned* wgHist  = sorted;                    // overlays sorted until part2
        unsigned* entries = sorted + E;                // tail
        unsigned short* colslab = (unsigned short*)(entries + E);
        __half*   xs      = (__half*)entries;          // overlays entries+colslab after mid

        k_histdump<<<nWG, B, 0, stream>>>(row, col, wgHist, E);
        k_scan2a<<<512, B, 0, stream>>>(wgHist, binTot, nWG);
        k_scan2b<<<1, B, 0, stream>>>(binTot, baseR, baseC, nodeBeg, E, N);
        k_part2<<<nWG, B, 0, stream>>>(row, col, wgHist, baseR, baseC, entries, colslab, E);
        k_mid<<<2 * nBkt, B, 0, stream>>>(entries, sorted, baseR, nodeBeg,
                                          colslab, baseC, dis, N, nBkt);
        k_scale<<<(N * (D_FEAT / 4) + B - 1) / B, B, 0, stream>>>(x, dis, xs, N);
        long long gthreads = (long long)N * 64;
        k_gather<<<(int)((gthreads + B - 1) / B), B, 0, stream>>>(
            x, xs, dis, nodeBeg, sorted, out, N);
    } else {
        // fallback: atomic scatter (needs only N floats of ws)
        float* deg = (float*)d_ws;
        k_init_deg<<<(N + B - 1) / B, B, 0, stream>>>(deg, N);
        k_count_deg<<<(E + B - 1) / B, B, 0, stream>>>(col, deg, E);
        k_deg_to_dis<<<(N + B - 1) / B, B, 0, stream>>>(deg, N);
        int total = N * D_FEAT;
        k_self_init<<<(total + B - 1) / B, B, 0, stream>>>(x, deg, out, total);
        long long st = (long long)E * 64;
        k_scatter<<<(int)((st + B - 1) / B), B, 0, stream>>>(row, col, x, deg, out, E);
    }
}